// Round 3
// baseline (136.902 us; speedup 1.0000x reference)
//
#include <hip/hip_runtime.h>
#include <hip/hip_bf16.h>

// out[i] = y[i] * w[idx] + b[idx],  idx = (t<<10) | x-row bits (MSB first).
// N = 2,000,000 = 128 * 15625 (exact), D = 10, C = 2048.
// Memory floor: ~104 MB traffic -> ~17 us at 6.3 TB/s.
//
// R3: double-buffered global_load_lds + register prefetch of t/y with
// PARTIAL vmcnt waits (steady-state waits vmcnt(9), never 0): tile i's
// loads were issued one full iteration earlier, so the wait is ~free.
// w/b fused into one float2 LDS table -> single ds_read_b64 gather.

#define D        10
#define TILE     128
#define WPB      4
#define BLOCKS   1024
#define NTHREADS 256

// s_waitcnt imm (gfx9 encoding): vmcnt[3:0]|[15:14], expcnt[6:4], lgkmcnt[11:8]
#define WAITCNT_VM9 0x0F79   // vmcnt<=9, lgkm/exp don't-care
#define WAITCNT_VM0 0x0F70   // vmcnt<=0

__device__ __forceinline__ void dma16(const void* g, void* l) {
    __builtin_amdgcn_global_load_lds(
        (const __attribute__((address_space(1))) void*)g,
        (__attribute__((address_space(3))) void*)l, 16, 0, 0);
}

__device__ __forceinline__ int make_idx(const float* row, float tt) {
    const float2* p = (const float2*)row;   // 8B-aligned (40 B row stride)
    float2 a0 = p[0], a1 = p[1], a2 = p[2], a3 = p[3], a4 = p[4];
    float v = a0.x;
    v = fmaf(v, 2.f, a0.y);
    v = fmaf(v, 2.f, a1.x);
    v = fmaf(v, 2.f, a1.y);
    v = fmaf(v, 2.f, a2.x);
    v = fmaf(v, 2.f, a2.y);
    v = fmaf(v, 2.f, a3.x);
    v = fmaf(v, 2.f, a3.y);
    v = fmaf(v, 2.f, a4.x);
    v = fmaf(v, 2.f, a4.y);
    v = fmaf(tt, 1024.f, v);   // t is MSB
    return (int)v;
}

__global__ __launch_bounds__(NTHREADS, 2) void enc_kernel(
    const float* __restrict__ x,   // [N,10]
    const float* __restrict__ t,   // [N]
    const float* __restrict__ y,   // [N]
    const float* __restrict__ w,   // [2048]
    const float* __restrict__ b,   // [2048]
    float* __restrict__ out,       // [N]
    int nTiles, int stride)
{
    __shared__ float2 lwb[2048];               // 16 KB fused w/b table
    __shared__ float xs[WPB][2][TILE * D];     // 4 waves x 2 bufs x 5120 B

    const int tid = threadIdx.x;

    // Stage fused table: 2048 entries, 256 threads x 8.
    {
        const float4* w4 = (const float4*)w;
        const float4* b4 = (const float4*)b;
        #pragma unroll
        for (int k = 0; k < 2; ++k) {
            float4 fw = w4[tid * 2 + k];
            float4 fb = b4[tid * 2 + k];
            int base = (tid * 2 + k) * 4;
            lwb[base + 0] = make_float2(fw.x, fb.x);
            lwb[base + 1] = make_float2(fw.y, fb.y);
            lwb[base + 2] = make_float2(fw.z, fb.z);
            lwb[base + 3] = make_float2(fw.w, fb.w);
        }
    }
    __syncthreads();

    const int wave = tid >> 6;
    const int lane = tid & 63;
    float* bufs[2] = { xs[wave][0], xs[wave][1] };

    int tile = blockIdx.x * WPB + wave;
    if (tile >= nTiles) return;

    // Prologue: prefetch tile 0's x-tile (DMA) and t/y (registers).
    {
        const char* g = (const char*)x + (size_t)tile * (TILE * D * 4);
        #pragma unroll
        for (int k = 0; k < 5; ++k)
            dma16(g + k * 1024 + lane * 16, (char*)bufs[0] + k * 1024);
    }
    int r0 = tile * TILE + lane;
    float tc0 = t[r0], tc1 = t[r0 + 64];
    float yc0 = y[r0], yc1 = y[r0 + 64];

    int cb = 0;
    while (tile < nTiles) {
        const int next = tile + stride;
        const bool hn = next < nTiles;
        float tn0 = 0.f, tn1 = 0.f, yn0 = 0.f, yn1 = 0.f;
        if (hn) {
            // Issue next tile's 5 DMAs + 4 t/y loads BEFORE consuming current.
            const char* g = (const char*)x + (size_t)next * (TILE * D * 4);
            #pragma unroll
            for (int k = 0; k < 5; ++k)
                dma16(g + k * 1024 + lane * 16, (char*)bufs[cb ^ 1] + k * 1024);
            const int nr0 = next * TILE + lane;
            tn0 = t[nr0]; tn1 = t[nr0 + 64];
            yn0 = y[nr0]; yn1 = y[nr0 + 64];
        }

        __asm__ volatile("" ::: "memory");
        if (hn) __builtin_amdgcn_s_waitcnt(WAITCNT_VM9);  // only cur's 9 must land
        else    __builtin_amdgcn_s_waitcnt(WAITCNT_VM0);
        __asm__ volatile("" ::: "memory");

        const float* xw = bufs[cb];
        const int i0 = make_idx(xw + lane * D, tc0);
        const int i1 = make_idx(xw + (lane + 64) * D, tc1);
        const float2 wb0 = lwb[i0];
        const float2 wb1 = lwb[i1];
        const int o0 = tile * TILE + lane;
        out[o0]      = fmaf(yc0, wb0.x, wb0.y);
        out[o0 + 64] = fmaf(yc1, wb1.x, wb1.y);

        tile = next;
        cb ^= 1;
        tc0 = tn0; tc1 = tn1; yc0 = yn0; yc1 = yn1;
    }
}

// Tail fallback (not hit at N=2,000,000).
__global__ __launch_bounds__(256) void enc_tail(
    const float* __restrict__ x, const float* __restrict__ t,
    const float* __restrict__ y, const float* __restrict__ w,
    const float* __restrict__ b, float* __restrict__ out,
    int start, int n)
{
    int i = start + blockIdx.x * blockDim.x + threadIdx.x;
    if (i >= n) return;
    const float* r = x + (size_t)i * D;
    float v = r[0];
    #pragma unroll
    for (int j = 1; j < D; ++j) v = fmaf(v, 2.f, r[j]);
    int idx = (int)fmaf(t[i], 1024.f, v);
    out[i] = fmaf(y[i], w[idx], b[idx]);
}

extern "C" void kernel_launch(void* const* d_in, const int* in_sizes, int n_in,
                              void* d_out, int out_size, void* d_ws, size_t ws_size,
                              hipStream_t stream) {
    const float* x = (const float*)d_in[0];
    const float* t = (const float*)d_in[1];
    const float* y = (const float*)d_in[2];
    const float* w = (const float*)d_in[3];
    const float* b = (const float*)d_in[4];
    float* out = (float*)d_out;

    const int n = out_size;            // 2,000,000
    const int nTiles = n / TILE;       // 15625 (exact here)
    const int rem = n - nTiles * TILE;

    enc_kernel<<<BLOCKS, NTHREADS, 0, stream>>>(x, t, y, w, b, out,
                                                nTiles, BLOCKS * WPB);
    if (rem > 0) {
        enc_tail<<<(rem + 255) / 256, 256, 0, stream>>>(
            x, t, y, w, b, out, nTiles * TILE, n);
    }
}